// Round 6
// baseline (921.443 us; speedup 1.0000x reference)
//
#include <hip/hip_runtime.h>

// Attractor net (all I/O float32): c = x@Win^T + bin; a=0; 15x: a = tanh(a@Ws^T + b + c),
// Ws = 0.5(W+W^T); y = a@Wout^T + bout.  x (65536,256), N=512, C=256.
//
// Round-7 (resubmit; round-6 bench was an infra failure, kernel audit found no defect):
// occupancy restructure for 8 waves/SIMD. (mt=1,nt=1) per wave:
//  - 16 waves/block = 16 m-tiles x 1 n-tile -> 32 samples/block, grid 2048,
//    2 blocks/CU, 32 waves/CU (8/SIMD) -- double the latency hiding of r2-r4,
//    which were all register-pinned at 4 waves/SIMD (128 regs/wave).
//  - Per-wave regs: acc 16 + c_pk 8 + A-pingpong 8 + B 4 + addr ~20 <= 64 total
//    (the 64-reg occupancy step). __launch_bounds__(1024,8) enforces the fit;
//    spill -> WRITE_SIZE explosion is the declared failure signature.
//  - Costs accepted: B-LDS and A-L2 traffic both 2x r2 (B-frag read 16x, full Ws
//    per 32 samples) -> floors: LDS 213us, L2 ~425us; both << current 854us.
//  - Serial region (acc re-init, tanh) shrinks 4x per wave; 2 blocks/CU overlap it.
//  - a in LDS bf16 (32 rows x 512 feat, XOR-swizzled 16B units), 32KB; y-stage
//    overlay 32x65 uint4 -> 33,280B per block.

using bf16x8 = __attribute__((ext_vector_type(8))) __bf16;
using f32x16 = __attribute__((ext_vector_type(16))) float;

// round-to-nearest bf16 pack of two floats into one u32 (lo = a, hi = b)
__device__ __forceinline__ unsigned int pack2bf(float a, float b) {
  unsigned int ua = __builtin_bit_cast(unsigned int, a);
  unsigned int ub = __builtin_bit_cast(unsigned int, b);
  return ((ua + 0x8000u) >> 16) | ((ub + 0x8000u) & 0xffff0000u);
}

__device__ __forceinline__ unsigned short f2bf(float v) {
  unsigned int u = __builtin_bit_cast(unsigned int, v);
  return (unsigned short)((u + 0x7fffu + ((u >> 16) & 1u)) >> 16);  // RNE
}

__device__ __forceinline__ float fast_tanh(float x) {
  // tanh(x) = 1 - 2/(e^{2x}+1);  e^{2x} = 2^{x*2*log2(e)}
  float e = __builtin_amdgcn_exp2f(x * 2.885390082f);
  float r = __builtin_amdgcn_rcpf(e + 1.0f);
  return __builtin_fmaf(-2.0f, r, 1.0f);
}

__device__ __forceinline__ f32x16 mfma32(uint4 a, uint4 b, f32x16 c) {
  return __builtin_amdgcn_mfma_f32_32x32x16_bf16(
      __builtin_bit_cast(bf16x8, a), __builtin_bit_cast(bf16x8, b), c, 0, 0, 0);
}

// ---------------- prep ----------------
// Task 1: WsP = bf16 A-fragment layout of 0.5*(W + W^T).
//   Fragment block (s, mtG) is 1KB: lane L holds Ws[m = mtG*32 + (L&31)][k = s*16 + (L>>5)*8 + j]
//   at element offset ((s*16+mtG)*64 + L)*8 + j.
// Task 2: row-major f32->bf16 copies of Win (131072 elems) and Wout (131072 elems).
__global__ void prep(const float* __restrict__ W,
                     const float* __restrict__ Win,
                     const float* __restrict__ Wout,
                     unsigned short* __restrict__ WsPo,
                     unsigned short* __restrict__ WinBf,
                     unsigned short* __restrict__ WoutBf) {
  int t = blockIdx.x * 256 + threadIdx.x;   // 0 .. 262143
  int e   = t & 511;
  int bid = t >> 9;
  int s  = bid >> 4;
  int mt = bid & 15;
  int L = e >> 3, j = e & 7;
  int m = mt * 32 + (L & 31);
  int k = s * 16 + (L >> 5) * 8 + j;
  WsPo[t] = f2bf(0.5f * (W[m * 512 + k] + W[k * 512 + m]));
  if (t < 131072) WinBf[t] = f2bf(Win[t]);
  else            WoutBf[t - 131072] = f2bf(Wout[t - 131072]);
}

// ---------------- main fused kernel ----------------
__global__ __launch_bounds__(1024, 8) void attractor_kernel(
    const float* __restrict__ x,              // 65536 x 256 f32
    const unsigned short* __restrict__ WinBf, // 512 x 256 bf16
    const float* __restrict__ binf,           // 512 f32
    const float* __restrict__ brecf,          // 512 f32
    const unsigned short* __restrict__ WoutBf,// 256 x 512 bf16
    const float* __restrict__ boutf,          // 256 f32
    const uint4* __restrict__ WsP,            // packed 512 KB bf16
    float* __restrict__ y)                    // 65536 x 256 f32
{
  __shared__ uint4 smem4[2080];               // 33,280 B (a: 32KB; y-stage: 32x65 uint4)
  unsigned long long* a_sh = (unsigned long long*)smem4;

  const int tid  = threadIdx.x;
  const int lane = tid & 63;
  const int w    = tid >> 6;    // wave 0..15 = m-tile (feature rows [w*32, w*32+32))
  const int il   = lane & 31;   // row-within-32-tile; also the 5-bit LDS swizzle key
  const int g    = lane >> 5;   // k-group (0/1)
  const int sw   = w * 2;       // per-wave K-sweep stagger (16 waves x 2 covers 32 slices)
  const int blk  = blockIdx.x;

  const float4* __restrict__ xf4  = (const float4*)x;       // row = 64 float4
  const uint4* __restrict__ Win4  = (const uint4*)WinBf;    // row = 32 uint4
  const uint4* __restrict__ Wout4 = (const uint4*)WoutBf;   // row = 64 uint4
  uint4* __restrict__ y4 = (uint4*)y;                       // row = 64 uint4

  f32x16 acc;                   // 16 regs
  unsigned int c_pk[8];         // 8 regs

  // ---------- Phase 1: in_proj  c^T = Win @ x^T  (K = 256 -> 16 steps) ----------
  #pragma unroll
  for (int r = 0; r < 16; ++r) acc[r] = 0.0f;

  #pragma unroll 2
  for (int s = 0; s < 16; ++s) {
    const int m = w * 32 + il;                 // feature row of Win
    uint4 A = Win4[m * 32 + 2 * s + g];
    const int i = blk * 32 + il;               // sample row of x
    float4 f0 = xf4[i * 64 + 4 * s + 2 * g + 0];
    float4 f1 = xf4[i * 64 + 4 * s + 2 * g + 1];
    uint4 B;
    B.x = pack2bf(f0.x, f0.y);
    B.y = pack2bf(f0.z, f0.w);
    B.z = pack2bf(f1.x, f1.y);
    B.w = pack2bf(f1.z, f1.w);
    acc = mfma32(A, B, acc);
  }

  // epilogue: fold biases into c, stash packed c
  #pragma unroll
  for (int p = 0; p < 4; ++p) {
    const int n0 = w * 32 + 8 * p + 4 * g;
    acc[4 * p + 0] += binf[n0 + 0] + brecf[n0 + 0];
    acc[4 * p + 1] += binf[n0 + 1] + brecf[n0 + 1];
    acc[4 * p + 2] += binf[n0 + 2] + brecf[n0 + 2];
    acc[4 * p + 3] += binf[n0 + 3] + brecf[n0 + 3];
    c_pk[2 * p + 0] = pack2bf(acc[4 * p + 0], acc[4 * p + 1]);
    c_pk[2 * p + 1] = pack2bf(acc[4 * p + 2], acc[4 * p + 3]);
  }

  // tanh + swizzled bf16 store of a into LDS.
  // 16B-unit index v_w = w*4 + p (wave-constant), half g; swizzle: pos = v_w ^ il.
  auto tanhStore = [&]() {
    #pragma unroll
    for (int p = 0; p < 4; ++p) {
      float t0 = fast_tanh(acc[4 * p + 0]);
      float t1 = fast_tanh(acc[4 * p + 1]);
      float t2 = fast_tanh(acc[4 * p + 2]);
      float t3 = fast_tanh(acc[4 * p + 3]);
      unsigned long long qv =
          (unsigned long long)pack2bf(t0, t1) |
          ((unsigned long long)pack2bf(t2, t3) << 32);
      const int v_w = w * 4 + p;               // 16B unit within 64-unit row
      a_sh[il * 128 + (((v_w ^ il) << 1) | g)] = qv;
    }
  };
  tanhStore();

  // cross-barrier prefetch of the first Ws fragment (it=0, se=sw)
  const uint4* pA = WsP + w * 64 + lane;       // + se*1024
  uint4 Ab[2];                                 // A double buffer (8 regs)
  Ab[0] = pA[sw * 1024];

  __syncthreads();

  // ---------- Phase 2: 14 iterations  z^T = Ws @ a^T  (K = 512 -> 32 steps) ----------
  #pragma unroll 1
  for (int it = 0; it < 14; ++it) {
    // acc <- c (bf16-unpacked; biases already folded in)
    #pragma unroll
    for (int p = 0; p < 4; ++p) {
      unsigned int u01 = c_pk[2 * p + 0];
      unsigned int u23 = c_pk[2 * p + 1];
      acc[4 * p + 0] = __builtin_bit_cast(float, u01 << 16);
      acc[4 * p + 1] = __builtin_bit_cast(float, u01 & 0xffff0000u);
      acc[4 * p + 2] = __builtin_bit_cast(float, u23 << 16);
      acc[4 * p + 3] = __builtin_bit_cast(float, u23 & 0xffff0000u);
    }

    #pragma unroll 2
    for (int s = 0; s < 32; ++s) {
      const int se = (s + sw) & 31;            // this wave's staggered K-step
      const int sn = (s + 1 + sw) & 31;        // at s=31 wraps to sw = next iter's first
      Ab[(s + 1) & 1] = pA[sn * 1024];         // A(s+1) prefetch (crosses iter boundary)
      uint4 B = smem4[il * 64 + ((2 * se + g) ^ il)];   // one ds_read_b128
      acc = mfma32(Ab[s & 1], B, acc);
    }
    __syncthreads();   // all reads of old a done
    tanhStore();       // overwrite a in place  (Ab[0] already holds next-iter fragment)
    __syncthreads();   // new a visible to all waves
  }

  // ---------- Phase 3: out_proj  y^T = Wout @ a^T (waves 0..7; channels [w*32,+32)) ----------
  f32x16 o;
  #pragma unroll
  for (int r = 0; r < 16; ++r) o[r] = 0.0f;

  if (w < 8) {
    #pragma unroll 2
    for (int s = 0; s < 32; ++s) {
      const int se = (s + sw) & 31;
      const int m = w * 32 + il;               // output-channel row of Wout
      uint4 A = Wout4[m * 64 + 2 * se + g];
      uint4 B = smem4[il * 64 + ((2 * se + g) ^ il)];
      o = mfma32(A, B, o);
    }
  }
  __syncthreads();   // done reading a; reuse LDS as y staging

  // epilogue: +bout, stage f32 rows into LDS (stride-65 uint4 rows)
  uint4* yst4 = smem4;
  if (w < 8) {
    #pragma unroll
    for (int p = 0; p < 4; ++p) {
      const int c0 = w * 32 + 8 * p + 4 * g;
      float4 r;
      r.x = o[4 * p + 0] + boutf[c0 + 0];
      r.y = o[4 * p + 1] + boutf[c0 + 1];
      r.z = o[4 * p + 2] + boutf[c0 + 2];
      r.w = o[4 * p + 3] + boutf[c0 + 3];
      yst4[il * 65 + (c0 >> 2)] = __builtin_bit_cast(uint4, r);
    }
  }
  __syncthreads();

  // coalesced f32 store: 2048 uint4 per block, 2 passes x 1024 threads
  #pragma unroll
  for (int p = 0; p < 2; ++p) {
    int idx = p * 1024 + tid;
    int row = idx >> 6;
    int col = idx & 63;
    y4[(blk * 32 + row) * 64 + col] = yst4[row * 65 + col];
  }
}

extern "C" void kernel_launch(void* const* d_in, const int* in_sizes, int n_in,
                              void* d_out, int out_size, void* d_ws, size_t ws_size,
                              hipStream_t stream) {
  const float* x    = (const float*)d_in[0];
  const float* Win  = (const float*)d_in[1];
  const float* bin  = (const float*)d_in[2];
  const float* W    = (const float*)d_in[3];
  const float* brec = (const float*)d_in[4];
  const float* Wout = (const float*)d_in[5];
  const float* bout = (const float*)d_in[6];

  unsigned short* wsu    = (unsigned short*)d_ws;
  unsigned short* WsP    = wsu;            // 262144 bf16 = 512 KB
  unsigned short* WinBf  = wsu + 262144;   // 131072 bf16 = 256 KB
  unsigned short* WoutBf = wsu + 393216;   // 131072 bf16 = 256 KB

  prep<<<1024, 256, 0, stream>>>(W, Win, Wout, WsP, WinBf, WoutBf);
  attractor_kernel<<<2048, 1024, 0, stream>>>(x, WinBf, bin, brec, WoutBf, bout,
                                              (const uint4*)WsP, (float*)d_out);
}